// Round 5
// baseline (3798.225 us; speedup 1.0000x reference)
//
// Persistent cooperative LSTM kernel for MI355X (gfx950) — round 5.
//  - R5 vs R3/R4 (which were MALL-broadcast + serialized-drain bound;
//    R4 proved local-L2 caching is impossible for cross-XCD write-through data):
//    (a) 128 blocks x 512 threads: block owns 8 hidden units (32 gate cols =
//        2 col-tiles), 8 waves = 2 ctiles x 4 K-quarters. Halves aggregate
//        MALL broadcast traffic per pass (16MB vs 32MB); 8 waves/CU hide
//        MALL latency; 128 barrier participants.
//    (b) pipelined mm: 2-deep rotating 8-load batches with partial
//        s_waitcnt vmcnt(8) — MFMA overlaps outstanding loads. Safe by
//        construction: wait(8) ensures all but the 8 newest vm-ops retired,
//        and each consumed batch has exactly 8 newer loads behind it.
//    (c) back to small ws (~4.7MB): 2-cycle h buffers + 32 relu slots,
//        sc0 sc1 write-through stores + sc0 sc1 loads (proven R3 path).
//  - Grid barrier: 8 flag lines x 16 pollers, no fences (release = vmcnt
//    drain of write-through stores; acquire = coherent loads).
#include <hip/hip_runtime.h>

typedef __attribute__((ext_vector_type(8))) short short8;
typedef __attribute__((ext_vector_type(4))) int int4_;
typedef __attribute__((ext_vector_type(4))) float float4_;

#define AGENT __HIP_MEMORY_SCOPE_AGENT

__device__ __forceinline__ unsigned short f2bf(float f) {
    unsigned u = __builtin_bit_cast(unsigned, f);
    u = (u + 0x7FFFu + ((u >> 16) & 1u)) >> 16;
    return (unsigned short)u;
}
__device__ __forceinline__ float bf2f(unsigned short h) {
    unsigned u = ((unsigned)h) << 16;
    return __builtin_bit_cast(float, u);
}
__device__ __forceinline__ float sigm(float x) { return 1.0f / (1.0f + __expf(-x)); }
__device__ __forceinline__ float tanhf_(float x) {
    x = fminf(fmaxf(x, -15.0f), 15.0f);
    float e = __expf(2.0f * x);
    return (e - 1.0f) / (e + 1.0f);
}

__device__ __forceinline__ void st16_coh(unsigned short* p, int4_ v) {
    asm volatile("global_store_dwordx4 %0, %1, off sc0 sc1" :: "v"(p), "v"(v) : "memory");
}

// ---- grid barrier: 8 groups of 16 blocks; no fences ----
__device__ __forceinline__ void gbar(unsigned* bar, unsigned target, int grpId) {
    asm volatile("s_waitcnt vmcnt(0)" ::: "memory");
    __syncthreads();
    if (threadIdx.x == 0) {
        unsigned old = __hip_atomic_fetch_add(bar + 256 + grpId * 16, 1u, __ATOMIC_RELAXED, AGENT);
        if ((old & 15u) == 15u) {
            unsigned old2 = __hip_atomic_fetch_add(bar + 512, 1u, __ATOMIC_RELAXED, AGENT);
            if ((old2 & 7u) == 7u) {
#pragma unroll
                for (int g = 0; g < 8; g++)
                    __hip_atomic_store(bar + g * 16, target, __ATOMIC_RELAXED, AGENT);
            }
        }
        while (__hip_atomic_load(bar + grpId * 16, __ATOMIC_RELAXED, AGENT) < target)
            __builtin_amdgcn_s_sleep(2);
    }
    __syncthreads();
}

__device__ __forceinline__ void zero4(float4_ (&a)[4]) {
    float4_ z;
    z[0] = 0.f; z[1] = 0.f; z[2] = 0.f; z[3] = 0.f;
#pragma unroll
    for (int i = 0; i < 4; i++) a[i] = z;
}

#define LD_COH(dst, base, OFF) \
    asm volatile("global_load_dwordx4 %0, %1, off offset:" #OFF " sc0 sc1" \
                 : "=v"(dst) : "v"(base))

#define ISSUE8(F, AR) \
    do { LD_COH(F[0], AR, 0);   LD_COH(F[1], AR, 64);  LD_COH(F[2], AR, 128); \
         LD_COH(F[3], AR, 192); LD_COH(F[4], AR, 256); LD_COH(F[5], AR, 320); \
         LD_COH(F[6], AR, 384); LD_COH(F[7], AR, 448); } while (0)

#define WAITV(N, F) \
    asm volatile("s_waitcnt vmcnt(" #N ")" \
                 : "+v"(F[0]), "+v"(F[1]), "+v"(F[2]), "+v"(F[3]), \
                   "+v"(F[4]), "+v"(F[5]), "+v"(F[6]), "+v"(F[7]))

#define MFMA8(F, BF, ACCI) \
    do { _Pragma("unroll") \
         for (int s_ = 0; s_ < 8; s_++) \
             ACCI = __builtin_amdgcn_mfma_f32_16x16x32_bf16( \
                 __builtin_bit_cast(short8, F[s_]), BF[s_], ACCI, 0, 0, 0); } while (0)

// A row-major [64][1024] bf16. A-frag: m = lane&15 (+16*mt), k = quad*8+j.
// Pipelined: 2-deep rotating 8-load batches, partial vmcnt(8) waits.
__device__ __forceinline__ void mm_pipe(const unsigned short* __restrict__ A,
                                        int q, int lane,
                                        const short8 (&bf)[8], float4_ (&acc)[4]) {
    const int r0 = lane & 15;
    const int kq = (q << 8) + ((lane >> 4) << 3);
    const unsigned short* Ar0 = A + r0 * 1024 + kq;
    const unsigned short* Ar1 = Ar0 + 16 * 1024;
    const unsigned short* Ar2 = Ar0 + 32 * 1024;
    const unsigned short* Ar3 = Ar0 + 48 * 1024;
    int4_ fA[8], fB[8];
    ISSUE8(fA, Ar0);
    ISSUE8(fB, Ar1);
    WAITV(8, fA);
    MFMA8(fA, bf, acc[0]);
    ISSUE8(fA, Ar2);
    WAITV(8, fB);
    MFMA8(fB, bf, acc[1]);
    ISSUE8(fB, Ar3);
    WAITV(8, fA);
    MFMA8(fA, bf, acc[2]);
    WAITV(0, fB);
    MFMA8(fB, bf, acc[3]);
}

// gparts region index: [ct][q][row 64][col 16+pad]
__device__ __forceinline__ int gidx(int ct, int q, int row, int col) {
    return ((ct * 4 + q) * 64 + row) * 17 + col;
}

__device__ __forceinline__ void write_parts(float* gp, int ct, int q, int lane,
                                            float4_ (&acc)[4]) {
    const int col = lane & 15;
    const int rbase = (lane >> 4) * 4;
#pragma unroll
    for (int mt = 0; mt < 4; mt++)
#pragma unroll
        for (int r = 0; r < 4; r++)
            gp[gidx(ct, q, mt * 16 + rbase + r, col)] = acc[mt][r];
}

__device__ __forceinline__ float gsum(const float* gp, int ct, int b, int c) {
    return gp[gidx(ct, 0, b, c)] + gp[gidx(ct, 1, b, c)] +
           gp[gidx(ct, 2, b, c)] + gp[gidx(ct, 3, b, c)];
}

__device__ __forceinline__ short8 packrow(const float* __restrict__ p) {
    short8 r;
#pragma unroll
    for (int j = 0; j < 8; j++) r[j] = (short)f2bf(p[j]);
    return r;
}

__global__ void __launch_bounds__(512, 1)
lstm_core(const float* __restrict__ x, const float* __restrict__ lastp,
          const float* __restrict__ Wih0, const float* __restrict__ Whh0,
          const float* __restrict__ bih0, const float* __restrict__ bhh0,
          const float* __restrict__ Wih1, const float* __restrict__ Whh1,
          const float* __restrict__ bih1, const float* __restrict__ bhh1,
          const float* __restrict__ W1, const float* __restrict__ b1,
          const float* __restrict__ W2, const float* __restrict__ b2,
          float* __restrict__ out, unsigned char* __restrict__ wsb)
{
    const int tid = threadIdx.x;
    const int blk = blockIdx.x;
    const int lane = tid & 63;
    const int wv = tid >> 6;         // wave 0..7
    const int q = wv >> 1;           // K quarter
    const int ct = wv & 1;           // col-tile (16 cols each; block has 32)
    const int grpId = blk & 7;
    const int eb = tid >> 3;         // epilogue: batch row 0..63
    const int eu = tid & 7;          // epilogue: unit-within-block 0..7
    const int D_ = blk * 8 + eu;     // global hidden unit / fc dim

    unsigned* bar = (unsigned*)wsb;
    unsigned short* h0buf[2] = {(unsigned short*)(wsb + 8192),
                                (unsigned short*)(wsb + 8192 + 131072)};
    unsigned short* h1buf[2] = {(unsigned short*)(wsb + 270336),
                                (unsigned short*)(wsb + 270336 + 131072)};
    unsigned short* relub = (unsigned short*)(wsb + 532480); // 32 x [64][1024]

    __shared__ float gparts[8 * 64 * 17];
    __shared__ float xlds[64 * 21];
    __shared__ float wih0l[32 * 20];
    __shared__ int4_ hstage4[64];
    unsigned short* hstage = (unsigned short*)hstage4;

    // ---- barrier area init (block 0) ----
    if (blk == 0 && tid == 0) {
        for (int g = 0; g < 8; g++) {
            __hip_atomic_store(bar + g * 16, 0u, __ATOMIC_RELAXED, AGENT);
            __hip_atomic_store(bar + 256 + g * 16, 0u, __ATOMIC_RELAXED, AGENT);
        }
        __hip_atomic_store(bar + 512, 0u, __ATOMIC_RELAXED, AGENT);
        __hip_atomic_store(bar + 544, 0x1357BDFu, __ATOMIC_RELEASE, AGENT);
    }

    // ---- per-lane B-fragment preload (bf16, RNE) ----
    const int n_ = lane & 15;                 // col within this wave's ctile
    const int cl_ = ct * 16 + n_;             // col within block (0..31)
    const int gq_ = cl_ >> 3, uu_ = cl_ & 7;  // gate, unit
    const int growL = gq_ * 1024 + blk * 8 + uu_;   // gate row for this col
    const int kq = (q << 8) + ((lane >> 4) << 3);

    short8 whh0f[8], wih1f[8], whh1f[8], wfusedf[8], wfcf[8];
#pragma unroll
    for (int s = 0; s < 8; s++) {
        const int k = kq + s * 32;
        whh0f[s] = packrow(Whh0 + growL * 1024 + k);
        wih1f[s] = packrow(Wih1 + growL * 1024 + k);
        whh1f[s] = packrow(Whh1 + growL * 1024 + k);
        { // Wfused[row][k] = sum_m Wih0[row][m] * W2[m][k]
            float a8[8] = {0.f, 0.f, 0.f, 0.f, 0.f, 0.f, 0.f, 0.f};
            for (int m = 0; m < 20; m++) {
                float wvv = Wih0[growL * 20 + m];
                const float* w2p = W2 + m * 1024 + k;
#pragma unroll
                for (int j = 0; j < 8; j++) a8[j] += wvv * w2p[j];
            }
            short8 r;
#pragma unroll
            for (int j = 0; j < 8; j++) r[j] = (short)f2bf(a8[j]);
            wfusedf[s] = r;
        }
        { // fc B (ct0 waves only): cols 0-7 = W1h rows, cols 8-15 = Wskip rows
            short8 r;
            if (ct == 0 && n_ < 8) {
                r = packrow(W1 + (blk * 8 + n_) * 1040 + k);
            } else if (ct == 0) {   // n_ in 8..15 -> Wskip for unit n_-8
                const int D = blk * 8 + (n_ - 8);
                float a8[8] = {0.f, 0.f, 0.f, 0.f, 0.f, 0.f, 0.f, 0.f};
                for (int g2 = 0; g2 < 16; g2++) {
                    const int m = 5 * (g2 >> 2) + (g2 & 3);
                    float wvv = W1[D * 1040 + 1024 + g2] * 0.01f;
                    const float* w2p = W2 + m * 1024 + k;
#pragma unroll
                    for (int j = 0; j < 8; j++) a8[j] += wvv * w2p[j];
                }
#pragma unroll
                for (int j = 0; j < 8; j++) r[j] = (short)f2bf(a8[j]);
            } else {
#pragma unroll
                for (int j = 0; j < 8; j++) r[j] = 0;
            }
            wfcf[s] = r;
        }
    }

    // ---- per-thread constants (epilogue: eb = tid>>3, eu = tid&7) ----
    float bias0g[4], bias1g[4], cgv[4];
#pragma unroll
    for (int g = 0; g < 4; g++) {
        const int row = g * 1024 + D_;
        bias0g[g] = bih0[row] + bhh0[row];
        bias1g[g] = bih1[row] + bhh1[row];
        float s = 0.f;
        for (int m = 0; m < 20; m++) s += Wih0[row * 20 + m] * b2[m];
        cgv[g] = s;
    }
    const float fcb = b1[D_];
    float cbv = 0.f, ustate = 0.f;
    for (int g2 = 0; g2 < 16; g2++) {
        const float w1v = W1[D_ * 1040 + 1024 + g2];
        cbv += b2[5 * (g2 >> 2) + (g2 & 3)] * w1v * 0.01f;
        ustate += lastp[eb * 16 + g2] * w1v;   // u(0) = lp0 @ W1lp^T
    }
    float c0v = 0.f, c1v = 0.f;

    if (tid < 32) { // Wih0 rows for x-path (fp32, exact); row_local = g*8+u
        const int row = (tid >> 3) * 1024 + blk * 8 + (tid & 7);
        for (int m = 0; m < 20; m++) wih0l[tid * 20 + m] = Wih0[row * 20 + m];
    }
    // zero initial h state (parity 1 is "t = -1"); coherent 16B stores
    if (tid < 64) {
        int4_ z; z[0] = 0; z[1] = 0; z[2] = 0; z[3] = 0;
        st16_coh(h0buf[1] + tid * 1024 + blk * 8, z);
        st16_coh(h1buf[1] + tid * 1024 + blk * 8, z);
    }

    if (tid == 0) {
        while (__hip_atomic_load(bar + 544, __ATOMIC_RELAXED, AGENT) != 0x1357BDFu)
            __builtin_amdgcn_s_sleep(2);
    }
    unsigned tgt = 1;
    gbar(bar, tgt++, grpId);

    // ---- phase lambdas ----
    auto stage_and_store = [&](unsigned short* dst, unsigned short val) {
        hstage[tid] = val;           // hstage[eb*8+eu] == hstage[tid]
        __syncthreads();
        if (tid < 64)
            st16_coh(dst + tid * 1024 + blk * 8, hstage4[tid]);
    };

    auto do_l0 = [&](const unsigned short* h0prev, unsigned short* h0dst,
                     const unsigned short* reluprev, int xt) {
        if (xt >= 0) {  // stage x BEFORE the pipelined mm (vmcnt accounting)
            for (int i = tid; i < 1280; i += 512) {
                const int bb = i / 20, mm = i - bb * 20;
                xlds[bb * 21 + mm] = x[bb * 1280 + xt * 20 + mm];
            }
            asm volatile("s_waitcnt vmcnt(0)" ::: "memory");
        }
        float4_ acc[4];
        zero4(acc);
        mm_pipe(h0prev, q, lane, whh0f, acc);
        if (reluprev) mm_pipe(reluprev, q, lane, wfusedf, acc);
        write_parts(gparts, ct, q, lane, acc);
        __syncthreads();
        float gv[4];
#pragma unroll
        for (int g = 0; g < 4; g++) {
            const int cl = g * 8 + eu;
            gv[g] = gsum(gparts, cl >> 4, eb, cl & 15) + bias0g[g];
        }
        if (xt >= 0) {
#pragma unroll
            for (int g = 0; g < 4; g++) {
                float s = 0.f;
                const float* wr = &wih0l[(g * 8 + eu) * 20];
                const float* xr = &xlds[eb * 21];
                for (int m = 0; m < 20; m++) s += xr[m] * wr[m];
                gv[g] += s;
            }
        } else {
#pragma unroll
            for (int g = 0; g < 4; g++) gv[g] += cgv[g];
        }
        const float iv = sigm(gv[0]), fv = sigm(gv[1]);
        const float gt = tanhf_(gv[2]), ov = sigm(gv[3]);
        c0v = fv * c0v + iv * gt;
        stage_and_store(h0dst, f2bf(ov * tanhf_(c0v)));
    };

    auto do_l1 = [&](const unsigned short* h0cur, const unsigned short* h1prev,
                     unsigned short* h1dst) {
        float4_ acc[4];
        zero4(acc);
        mm_pipe(h0cur, q, lane, wih1f, acc);
        mm_pipe(h1prev, q, lane, whh1f, acc);
        write_parts(gparts, ct, q, lane, acc);
        __syncthreads();
        float gv[4];
#pragma unroll
        for (int g = 0; g < 4; g++) {
            const int cl = g * 8 + eu;
            gv[g] = gsum(gparts, cl >> 4, eb, cl & 15) + bias1g[g];
        }
        const float iv = sigm(gv[0]), fv = sigm(gv[1]);
        const float gt = tanhf_(gv[2]), ov = sigm(gv[3]);
        c1v = fv * c1v + iv * gt;
        stage_and_store(h1dst, f2bf(ov * tanhf_(c1v)));
    };

    auto do_fc = [&](int t, const unsigned short* h1cur, const unsigned short* reluprev) {
        if (ct == 0) {   // only ctile-0 waves compute FC (cols 0-7 W1h, 8-15 Wskip)
            float4_ acc1[4], acc2[4];
            zero4(acc1);
            zero4(acc2);
            mm_pipe(h1cur, q, lane, wfcf, acc1);
            if (reluprev) mm_pipe(reluprev, q, lane, wfcf, acc2);
            write_parts(gparts, 0, q, lane, acc1);   // region 0: W1h @ h1
            write_parts(gparts, 1, q, lane, acc2);   // region 1: Wskip @ relu
        }
        __syncthreads();
        const float s1 = gsum(gparts, 0, eb, eu);
        if (t > 0) ustate += gsum(gparts, 1, eb, 8 + eu) + cbv;
        const float rv = fmaxf(s1 + ustate + fcb, 0.f);
        stage_and_store(relub + t * 65536, f2bf(rv));
    };

    // ---- encoder: 64 steps x {L0, barrier, L1} (post-L1 barrier elided) ----
    for (int t = 0; t < 64; t++) {
        do_l0(h0buf[(t + 1) & 1], h0buf[t & 1], nullptr, t);
        gbar(bar, tgt++, grpId);
        do_l1(h0buf[t & 1], h1buf[(t + 1) & 1], h1buf[t & 1]);
    }
    // ---- decoder: 32 steps x {L0, b, L1, b, FC, b} ----
    for (int t = 0; t < 32; t++) {
        const unsigned short* rp = (t > 0) ? (relub + (t - 1) * 65536) : nullptr;
        do_l0(h0buf[(t + 1) & 1], h0buf[t & 1], rp, (t == 0) ? 63 : -1);
        gbar(bar, tgt++, grpId);
        do_l1(h0buf[t & 1], h1buf[(t + 1) & 1], h1buf[t & 1]);
        gbar(bar, tgt++, grpId);
        do_fc(t, h1buf[t & 1], rp);
        gbar(bar, tgt++, grpId);
    }

    // ---- final: pred[t] = relu[t] @ W2^T + b2 -> out[b][t][m] ----
    {
        const int pj = tid >> 5;   // 16 (t,b) pairs per block
        const int m = tid & 31;
        if (m < 20) {
            const int pidx = blk * 16 + pj;
            const int tt = pidx >> 6, bb = pidx & 63;
            const unsigned short* rr = relub + tt * 65536 + bb * 1024;
            const float* w = W2 + m * 1024;
            float acc = 0.f;
            for (int k2 = 0; k2 < 1024; k2 += 8) {
                short8 r8 = *(const short8*)(rr + k2);
#pragma unroll
                for (int j = 0; j < 8; j++)
                    acc += bf2f((unsigned short)r8[j]) * w[k2 + j];
            }
            out[bb * 640 + tt * 20 + m] = acc + b2[m];
        }
    }
}

extern "C" void kernel_launch(void* const* d_in, const int* in_sizes, int n_in,
                              void* d_out, int out_size, void* d_ws, size_t ws_size,
                              hipStream_t stream) {
    (void)in_sizes; (void)n_in; (void)out_size; (void)ws_size;
    const float* x     = (const float*)d_in[0];
    const float* lastp = (const float*)d_in[1];
    const float* Wih0  = (const float*)d_in[2];
    const float* Whh0  = (const float*)d_in[3];
    const float* bih0  = (const float*)d_in[4];
    const float* bhh0  = (const float*)d_in[5];
    const float* Wih1  = (const float*)d_in[6];
    const float* Whh1  = (const float*)d_in[7];
    const float* bih1  = (const float*)d_in[8];
    const float* bhh1  = (const float*)d_in[9];
    const float* W1    = (const float*)d_in[10];
    const float* b1    = (const float*)d_in[11];
    const float* W2    = (const float*)d_in[12];
    const float* b2    = (const float*)d_in[13];
    float* out = (float*)d_out;
    unsigned char* ws = (unsigned char*)d_ws;

    void* args[] = {&x, &lastp, &Wih0, &Whh0, &bih0, &bhh0, &Wih1, &Whh1,
                    &bih1, &bhh1, &W1, &b1, &W2, &b2, &out, &ws};
    hipError_t err = hipLaunchCooperativeKernel((const void*)lstm_core,
                                                dim3(128), dim3(512), args, 0, stream);
    if (err != hipSuccess) {
        hipLaunchKernelGGL(lstm_core, dim3(128), dim3(512), 0, stream,
                           x, lastp, Wih0, Whh0, bih0, bhh0, Wih1, Whh1,
                           bih1, bhh1, W1, b1, W2, b2, out, ws);
    }
}

// Round 8
// 2447.869 us; speedup vs baseline: 1.5516x; 1.5516x over previous
//
// Persistent cooperative LSTM kernel for MI355X (gfx950) — round 8.
//  - BISECT ROUND: R3's EXACT schedule (proven pass, absmax 9.77e-4) with
//    R5's EXACT mm_pipe staging (proven numerically correct even under
//    spill). R6/R7's fused/retimed schedule produced bit-identical wrong
//    output under two different register allocations => semantic bug in the
//    fusion; shelved.
//  - 256 blocks x 256 threads, 1 block/CU, 4 waves = K-quarters. Weights in
//    VGPRs (160 regs); ~320 live < 512 cap at 1 wave/SIMD -> no spill.
//  - mm_pipe: 2-deep rotating 8x16B coherent loads, partial vmcnt(8) waits,
//    MFMA overlaps in-flight loads; each mm_pipe self-contained (ends
//    vmcnt(0)) so compiler-emitted loads between passes can't break the
//    accounting. x staged BEFORE the mm with vmcnt(0) drain (R5-proven).
//  - Everything else (gbar, buffers, epilogues, final pass) R3-verbatim.
#include <hip/hip_runtime.h>

typedef __attribute__((ext_vector_type(8))) short short8;
typedef __attribute__((ext_vector_type(4))) int int4_;
typedef __attribute__((ext_vector_type(4))) float float4_;

#define AGENT __HIP_MEMORY_SCOPE_AGENT

__device__ __forceinline__ unsigned short f2bf(float f) {
    unsigned u = __builtin_bit_cast(unsigned, f);
    u = (u + 0x7FFFu + ((u >> 16) & 1u)) >> 16;
    return (unsigned short)u;
}
__device__ __forceinline__ float bf2f(unsigned short h) {
    unsigned u = ((unsigned)h) << 16;
    return __builtin_bit_cast(float, u);
}
__device__ __forceinline__ float sigm(float x) { return 1.0f / (1.0f + __expf(-x)); }
__device__ __forceinline__ float tanhf_(float x) {
    x = fminf(fmaxf(x, -15.0f), 15.0f);
    float e = __expf(2.0f * x);
    return (e - 1.0f) / (e + 1.0f);
}

// coherent 8B store (write-through to coherence point)
__device__ __forceinline__ void st8_coh(unsigned short* p, unsigned long long v) {
    asm volatile("global_store_dwordx2 %0, %1, off sc0 sc1" :: "v"(p), "v"(v) : "memory");
}

// ---- grid barrier (R3-proven): no fences; release = vmcnt drain of the
// write-through stores; acquire = consumers use coherent loads ----
__device__ __forceinline__ void gbar(unsigned* bar, unsigned target, int grpId) {
    asm volatile("s_waitcnt vmcnt(0)" ::: "memory");
    __syncthreads();
    if (threadIdx.x == 0) {
        unsigned old = __hip_atomic_fetch_add(bar + 256 + grpId * 16, 1u, __ATOMIC_RELAXED, AGENT);
        if ((old & 15u) == 15u) {
            unsigned old2 = __hip_atomic_fetch_add(bar + 512, 1u, __ATOMIC_RELAXED, AGENT);
            if ((old2 & 15u) == 15u) {
#pragma unroll
                for (int g = 0; g < 16; g++)
                    __hip_atomic_store(bar + g * 16, target, __ATOMIC_RELAXED, AGENT);
            }
        }
        while (__hip_atomic_load(bar + grpId * 16, __ATOMIC_RELAXED, AGENT) < target)
            __builtin_amdgcn_s_sleep(2);
    }
    __syncthreads();
}

__device__ __forceinline__ void zero4(float4_ (&a)[4]) {
    float4_ z;
    z[0] = 0.f; z[1] = 0.f; z[2] = 0.f; z[3] = 0.f;
#pragma unroll
    for (int i = 0; i < 4; i++) a[i] = z;
}

// ---- R5-verbatim pipelined staging ----
#define LD_COH(dst, base, OFF) \
    asm volatile("global_load_dwordx4 %0, %1, off offset:" #OFF " sc0 sc1" \
                 : "=v"(dst) : "v"(base))

#define ISSUE8(F, AR) \
    do { LD_COH(F[0], AR, 0);   LD_COH(F[1], AR, 64);  LD_COH(F[2], AR, 128); \
         LD_COH(F[3], AR, 192); LD_COH(F[4], AR, 256); LD_COH(F[5], AR, 320); \
         LD_COH(F[6], AR, 384); LD_COH(F[7], AR, 448); } while (0)

#define WAITV(N, F) \
    asm volatile("s_waitcnt vmcnt(" #N ")" \
                 : "+v"(F[0]), "+v"(F[1]), "+v"(F[2]), "+v"(F[3]), \
                   "+v"(F[4]), "+v"(F[5]), "+v"(F[6]), "+v"(F[7]))

#define MFMA8(F, BF, ACCI) \
    do { _Pragma("unroll") \
         for (int s_ = 0; s_ < 8; s_++) \
             ACCI = __builtin_amdgcn_mfma_f32_16x16x32_bf16( \
                 __builtin_bit_cast(short8, F[s_]), BF[s_], ACCI, 0, 0, 0); } while (0)

// A row-major [64][1024] bf16. A-frag: m = lane&15 (+16*mt), k = quad*8+j.
// Pipelined: 2-deep rotating 8-load batches, partial vmcnt(8) waits.
// Self-contained: starts at vmcnt==0, ends with WAITV(0).
__device__ __forceinline__ void mm_pipe(const unsigned short* __restrict__ A,
                                        int q, int lane,
                                        const short8 (&bf)[8], float4_ (&acc)[4]) {
    const int r0 = lane & 15;
    const int kq = (q << 8) + ((lane >> 4) << 3);
    const unsigned short* Ar0 = A + r0 * 1024 + kq;
    const unsigned short* Ar1 = Ar0 + 16 * 1024;
    const unsigned short* Ar2 = Ar0 + 32 * 1024;
    const unsigned short* Ar3 = Ar0 + 48 * 1024;
    int4_ fA[8], fB[8];
    ISSUE8(fA, Ar0);
    ISSUE8(fB, Ar1);
    WAITV(8, fA);
    MFMA8(fA, bf, acc[0]);
    ISSUE8(fA, Ar2);
    WAITV(8, fB);
    MFMA8(fB, bf, acc[1]);
    ISSUE8(fB, Ar3);
    WAITV(8, fA);
    MFMA8(fA, bf, acc[2]);
    WAITV(0, fB);
    MFMA8(fB, bf, acc[3]);
}

// C[m][n]: n = lane&15, m = quad*4+reg  -> gp[(q*64+row)*17+col]
__device__ __forceinline__ void write_parts(float* gp, int q, int lane, float4_ (&acc)[4]) {
    const int col = lane & 15;
    const int rbase = (lane >> 4) * 4;
#pragma unroll
    for (int mt = 0; mt < 4; mt++)
#pragma unroll
        for (int r = 0; r < 4; r++)
            gp[(q * 64 + mt * 16 + rbase + r) * 17 + col] = acc[mt][r];
}

__device__ __forceinline__ float gsum(const float* gp, int b, int c) {
    return gp[(0 * 64 + b) * 17 + c] + gp[(1 * 64 + b) * 17 + c] +
           gp[(2 * 64 + b) * 17 + c] + gp[(3 * 64 + b) * 17 + c];
}

__device__ __forceinline__ short8 packrow(const float* __restrict__ p) {
    short8 r;
#pragma unroll
    for (int j = 0; j < 8; j++) r[j] = (short)f2bf(p[j]);
    return r;
}

__global__ void __launch_bounds__(256, 1)
lstm_core(const float* __restrict__ x, const float* __restrict__ lastp,
          const float* __restrict__ Wih0, const float* __restrict__ Whh0,
          const float* __restrict__ bih0, const float* __restrict__ bhh0,
          const float* __restrict__ Wih1, const float* __restrict__ Whh1,
          const float* __restrict__ bih1, const float* __restrict__ bhh1,
          const float* __restrict__ W1, const float* __restrict__ b1,
          const float* __restrict__ W2, const float* __restrict__ b2,
          float* __restrict__ out, unsigned char* __restrict__ wsb)
{
    const int tid = threadIdx.x;
    const int blk = blockIdx.x;
    const int lane = tid & 63;
    const int q = tid >> 6;          // wave id = K quarter
    const int grpId = blk & 15;
    const int eb = tid >> 2;         // epilogue: batch row
    const int eu = tid & 3;          // epilogue: unit-within-block
    const int D_ = blk * 4 + eu;     // global hidden unit / fc dim

    unsigned* bar = (unsigned*)wsb;
    // row-major bf16 buffers: h[b][1024]
    unsigned short* h0buf[2] = {(unsigned short*)(wsb + 8192),
                                (unsigned short*)(wsb + 8192 + 131072)};
    unsigned short* h1buf[2] = {(unsigned short*)(wsb + 270336),
                                (unsigned short*)(wsb + 270336 + 131072)};
    unsigned short* relub = (unsigned short*)(wsb + 532480); // 32 x [64][1024]

    __shared__ float gparts[4 * 64 * 17];
    __shared__ float xlds[64 * 21];
    __shared__ float wih0l[16 * 20];
    __shared__ unsigned long long hstage_u64[64];
    unsigned short* hstage = (unsigned short*)hstage_u64;

    // ---- barrier area init (block 0) ----
    if (blk == 0 && tid == 0) {
        for (int g = 0; g < 16; g++) {
            __hip_atomic_store(bar + g * 16, 0u, __ATOMIC_RELAXED, AGENT);
            __hip_atomic_store(bar + 256 + g * 16, 0u, __ATOMIC_RELAXED, AGENT);
        }
        __hip_atomic_store(bar + 512, 0u, __ATOMIC_RELAXED, AGENT);
        __hip_atomic_store(bar + 544, 0x1357BDFu, __ATOMIC_RELEASE, AGENT);
    }

    // ---- per-lane B-fragment preload (bf16, RNE) ----
    const int n_ = lane & 15;
    const int gq_ = n_ >> 2, uu_ = n_ & 3;
    const int growL = gq_ * 1024 + blk * 4 + uu_;   // gate row for this col
    const int kq = (q << 8) + ((lane >> 4) << 3);

    short8 whh0f[8], wih1f[8], whh1f[8], wfusedf[8], wfcf[8];
#pragma unroll
    for (int s = 0; s < 8; s++) {
        const int k = kq + s * 32;
        whh0f[s] = packrow(Whh0 + growL * 1024 + k);
        wih1f[s] = packrow(Wih1 + growL * 1024 + k);
        whh1f[s] = packrow(Whh1 + growL * 1024 + k);
        { // Wfused[row][k] = sum_m Wih0[row][m] * W2[m][k]
            float a8[8] = {0.f, 0.f, 0.f, 0.f, 0.f, 0.f, 0.f, 0.f};
            for (int m = 0; m < 20; m++) {
                float wv = Wih0[growL * 20 + m];
                const float* w2p = W2 + m * 1024 + k;
#pragma unroll
                for (int j = 0; j < 8; j++) a8[j] += wv * w2p[j];
            }
            short8 r;
#pragma unroll
            for (int j = 0; j < 8; j++) r[j] = (short)f2bf(a8[j]);
            wfusedf[s] = r;
        }
        { // fc B: cols 0-3 = W1h rows, cols 4-7 = Wskip rows, 8-15 = 0
            short8 r;
            if (n_ < 4) {
                r = packrow(W1 + (blk * 4 + n_) * 1040 + k);
            } else if (n_ < 8) {
                const int D = blk * 4 + (n_ - 4);
                float a8[8] = {0.f, 0.f, 0.f, 0.f, 0.f, 0.f, 0.f, 0.f};
                for (int g2 = 0; g2 < 16; g2++) {
                    const int m = 5 * (g2 >> 2) + (g2 & 3);
                    float wv = W1[D * 1040 + 1024 + g2] * 0.01f;
                    const float* w2p = W2 + m * 1024 + k;
#pragma unroll
                    for (int j = 0; j < 8; j++) a8[j] += wv * w2p[j];
                }
#pragma unroll
                for (int j = 0; j < 8; j++) r[j] = (short)f2bf(a8[j]);
            } else {
#pragma unroll
                for (int j = 0; j < 8; j++) r[j] = 0;
            }
            wfcf[s] = r;
        }
    }

    // ---- per-thread constants (epilogue mapping: eb = tid>>2, eu = tid&3) ----
    float bias0g[4], bias1g[4], cgv[4];
#pragma unroll
    for (int g = 0; g < 4; g++) {
        const int row = g * 1024 + D_;
        bias0g[g] = bih0[row] + bhh0[row];
        bias1g[g] = bih1[row] + bhh1[row];
        float s = 0.f;
        for (int m = 0; m < 20; m++) s += Wih0[row * 20 + m] * b2[m];
        cgv[g] = s;
    }
    const float fcb = b1[D_];
    float cbv = 0.f, ustate = 0.f;
    for (int g2 = 0; g2 < 16; g2++) {
        const float w1v = W1[D_ * 1040 + 1024 + g2];
        cbv += b2[5 * (g2 >> 2) + (g2 & 3)] * w1v * 0.01f;
        ustate += lastp[eb * 16 + g2] * w1v;   // u(0) = lp0 @ W1lp^T
    }
    float c0v = 0.f, c1v = 0.f;

    if (tid < 16) { // Wih0 rows for x-path (fp32, exact)
        const int row = (tid >> 2) * 1024 + blk * 4 + (tid & 3);
        for (int m = 0; m < 20; m++) wih0l[tid * 20 + m] = Wih0[row * 20 + m];
    }
    // zero initial h state (parity 1 is "t = -1"); coherent stores
    if (tid < 64) {
        st8_coh(h0buf[1] + tid * 1024 + blk * 4, 0ull);
        st8_coh(h1buf[1] + tid * 1024 + blk * 4, 0ull);
    }

    if (tid == 0) {
        while (__hip_atomic_load(bar + 544, __ATOMIC_RELAXED, AGENT) != 0x1357BDFu)
            __builtin_amdgcn_s_sleep(2);
    }
    unsigned tgt = 1;
    gbar(bar, tgt++, grpId);

    // ---- phase lambdas (R3-verbatim epilogues) ----
    auto stage_and_store = [&](unsigned short* dst, unsigned short val) {
        hstage[tid] = val;           // hstage[eb*4+eu] == hstage[tid]
        __syncthreads();
        if (tid < 64)
            st8_coh(dst + tid * 1024 + blk * 4, hstage_u64[tid]);
    };

    auto do_l0 = [&](const unsigned short* h0prev, unsigned short* h0dst,
                     const unsigned short* reluprev, int xt) {
        if (xt >= 0) {  // stage x BEFORE the pipelined mm (vmcnt accounting)
            for (int i = tid; i < 1280; i += 256) {
                const int bb = i / 20, mm = i - bb * 20;
                xlds[bb * 21 + mm] = x[bb * 1280 + xt * 20 + mm];
            }
            asm volatile("s_waitcnt vmcnt(0)" ::: "memory");
        }
        float4_ acc[4];
        zero4(acc);
        mm_pipe(h0prev, q, lane, whh0f, acc);
        if (reluprev) mm_pipe(reluprev, q, lane, wfusedf, acc);
        write_parts(gparts, q, lane, acc);
        __syncthreads();
        float gv[4];
#pragma unroll
        for (int g = 0; g < 4; g++) gv[g] = gsum(gparts, eb, g * 4 + eu) + bias0g[g];
        if (xt >= 0) {
#pragma unroll
            for (int g = 0; g < 4; g++) {
                float s = 0.f;
                const float* wr = &wih0l[(g * 4 + eu) * 20];
                const float* xr = &xlds[eb * 21];
                for (int m = 0; m < 20; m++) s += xr[m] * wr[m];
                gv[g] += s;
            }
        } else {
#pragma unroll
            for (int g = 0; g < 4; g++) gv[g] += cgv[g];
        }
        const float iv = sigm(gv[0]), fv = sigm(gv[1]);
        const float gt = tanhf_(gv[2]), ov = sigm(gv[3]);
        c0v = fv * c0v + iv * gt;
        stage_and_store(h0dst, f2bf(ov * tanhf_(c0v)));
    };

    auto do_l1 = [&](const unsigned short* h0cur, const unsigned short* h1prev,
                     unsigned short* h1dst) {
        float4_ acc[4];
        zero4(acc);
        mm_pipe(h0cur, q, lane, wih1f, acc);
        mm_pipe(h1prev, q, lane, whh1f, acc);
        write_parts(gparts, q, lane, acc);
        __syncthreads();
        float gv[4];
#pragma unroll
        for (int g = 0; g < 4; g++) gv[g] = gsum(gparts, eb, g * 4 + eu) + bias1g[g];
        const float iv = sigm(gv[0]), fv = sigm(gv[1]);
        const float gt = tanhf_(gv[2]), ov = sigm(gv[3]);
        c1v = fv * c1v + iv * gt;
        stage_and_store(h1dst, f2bf(ov * tanhf_(c1v)));
    };

    auto do_fc = [&](int t, const unsigned short* h1cur, const unsigned short* reluprev) {
        float4_ acc1[4], acc2[4];
        zero4(acc1);
        zero4(acc2);
        mm_pipe(h1cur, q, lane, wfcf, acc1);              // cols 0-3 valid: W1h@h1
        if (reluprev) mm_pipe(reluprev, q, lane, wfcf, acc2); // cols 4-7: Wskip@relu
        {
            const int col = lane & 15;
            const int rbase = (lane >> 4) * 4;
            if (col < 8) {
#pragma unroll
                for (int mt = 0; mt < 4; mt++)
#pragma unroll
                    for (int r = 0; r < 4; r++) {
                        const float v = (col < 4) ? acc1[mt][r] : acc2[mt][r];
                        gparts[(q * 64 + mt * 16 + rbase + r) * 17 + col] = v;
                    }
            }
        }
        __syncthreads();
        const float s1 = gsum(gparts, eb, eu);
        if (t > 0) ustate += gsum(gparts, eb, 4 + eu) + cbv;
        const float rv = fmaxf(s1 + ustate + fcb, 0.f);
        stage_and_store(relub + t * 65536, f2bf(rv));
    };

    // ---- encoder: 64 steps x {L0, barrier, L1} (post-L1 barrier elided) ----
    for (int t = 0; t < 64; t++) {
        do_l0(h0buf[(t + 1) & 1], h0buf[t & 1], nullptr, t);
        gbar(bar, tgt++, grpId);
        do_l1(h0buf[t & 1], h1buf[(t + 1) & 1], h1buf[t & 1]);
    }
    // ---- decoder: 32 steps x {L0, b, L1, b, FC, b} ----
    for (int t = 0; t < 32; t++) {
        const unsigned short* rp = (t > 0) ? (relub + (t - 1) * 65536) : nullptr;
        do_l0(h0buf[(t + 1) & 1], h0buf[t & 1], rp, (t == 0) ? 63 : -1);
        gbar(bar, tgt++, grpId);
        do_l1(h0buf[t & 1], h1buf[(t + 1) & 1], h1buf[t & 1]);
        gbar(bar, tgt++, grpId);
        do_fc(t, h1buf[t & 1], rp);
        gbar(bar, tgt++, grpId);
    }

    // ---- final: pred[t] = relu[t] @ W2^T + b2 -> out[b][t][m] ----
    {
        const int pj = tid >> 5;   // 8 (t,b) pairs per block
        const int m = tid & 31;
        if (m < 20) {
            const int pidx = blk * 8 + pj;
            const int tt = pidx >> 6, bb = pidx & 63;
            const unsigned short* rr = relub + tt * 65536 + bb * 1024;
            const float* w = W2 + m * 1024;
            float acc = 0.f;
            for (int k2 = 0; k2 < 1024; k2 += 8) {
                short8 r8 = *(const short8*)(rr + k2);
#pragma unroll
                for (int j = 0; j < 8; j++)
                    acc += bf2f((unsigned short)r8[j]) * w[k2 + j];
            }
            out[bb * 640 + tt * 20 + m] = acc + b2[m];
        }
    }
}

extern "C" void kernel_launch(void* const* d_in, const int* in_sizes, int n_in,
                              void* d_out, int out_size, void* d_ws, size_t ws_size,
                              hipStream_t stream) {
    (void)in_sizes; (void)n_in; (void)out_size; (void)ws_size;
    const float* x     = (const float*)d_in[0];
    const float* lastp = (const float*)d_in[1];
    const float* Wih0  = (const float*)d_in[2];
    const float* Whh0  = (const float*)d_in[3];
    const float* bih0  = (const float*)d_in[4];
    const float* bhh0  = (const float*)d_in[5];
    const float* Wih1  = (const float*)d_in[6];
    const float* Whh1  = (const float*)d_in[7];
    const float* bih1  = (const float*)d_in[8];
    const float* bhh1  = (const float*)d_in[9];
    const float* W1    = (const float*)d_in[10];
    const float* b1    = (const float*)d_in[11];
    const float* W2    = (const float*)d_in[12];
    const float* b2    = (const float*)d_in[13];
    float* out = (float*)d_out;
    unsigned char* ws = (unsigned char*)d_ws;

    void* args[] = {&x, &lastp, &Wih0, &Whh0, &bih0, &bhh0, &Wih1, &Whh1,
                    &bih1, &bhh1, &W1, &b1, &W2, &b2, &out, &ws};
    hipError_t err = hipLaunchCooperativeKernel((const void*)lstm_core,
                                                dim3(256), dim3(256), args, 0, stream);
    if (err != hipSuccess) {
        hipLaunchKernelGGL(lstm_core, dim3(256), dim3(256), 0, stream,
                           x, lastp, Wih0, Whh0, bih0, bhh0, Wih1, Whh1,
                           bih1, bhh1, W1, b1, W2, b2, out, ws);
    }
}